// Round 1
// baseline (68112.811 us; speedup 1.0000x reference)
//
#include <hip/hip_runtime.h>

#define BB 64
#define TT 2048
#define FF 15
#define UU 256
#define N3 768
#define NREG 80

// seq1 buffer: 64*2048*256 floats = 128 MiB (device global BSS)
__device__ float g_seq1[BB * TT * UU];

__global__ __launch_bounds__(768) void gru_l1(
    const float* __restrict__ x, const float* __restrict__ W1,
    const float* __restrict__ U1, const float* __restrict__ b1,
    float* __restrict__ out_state1)
{
    const int b = blockIdx.x;
    const int j = threadIdx.x;

    __shared__ float sW[FF * N3];        // 46080 B
    __shared__ float sbin[N3];
    __shared__ float sbrec[N3];
    __shared__ float h_s[UU];
    __shared__ float xrow[16];
    __shared__ float s_zsum[UU], s_rsum[UU], s_xp3[UU], s_rec3[UU];

    // stage W1 + biases into LDS
    for (int idx = j; idx < FF * N3; idx += N3) sW[idx] = W1[idx];
    sbin[j]  = b1[j];
    sbrec[j] = b1[N3 + j];
    if (j < UU) h_s[j] = 0.f;
    __syncthreads();

    // register-cache first NREG k-rows of U1 (column j)
    float ureg[NREG];
#pragma unroll
    for (int k = 0; k < NREG; k++) ureg[k] = U1[k * N3 + j];

    const float* xb  = x + (size_t)b * TT * FF;
    float* seqb      = g_seq1 + (size_t)b * TT * UU;

    for (int t = 0; t < TT; t++) {
        if (j < FF) xrow[j] = xb[t * FF + j];
        __syncthreads();

        // input projection (W1 from LDS)
        float xp = sbin[j];
#pragma unroll
        for (int k = 0; k < FF; k++) xp += xrow[k] * sW[k * N3 + j];

        // recurrent projection
        float rec = sbrec[j];
        const float4* h4 = (const float4*)h_s;
#pragma unroll
        for (int k4 = 0; k4 < NREG / 4; k4++) {
            float4 hv = h4[k4];
            rec += hv.x * ureg[4 * k4 + 0] + hv.y * ureg[4 * k4 + 1]
                 + hv.z * ureg[4 * k4 + 2] + hv.w * ureg[4 * k4 + 3];
        }
#pragma unroll 4
        for (int k4 = NREG / 4; k4 < UU / 4; k4++) {
            float4 hv = h4[k4];
            int k = 4 * k4;
            rec += hv.x * U1[(k + 0) * N3 + j] + hv.y * U1[(k + 1) * N3 + j]
                 + hv.z * U1[(k + 2) * N3 + j] + hv.w * U1[(k + 3) * N3 + j];
        }

        // publish gate pieces
        if (j < 2 * UU) {
            float a = xp + rec;
            if (j < UU) s_zsum[j] = a; else s_rsum[j - UU] = a;
        } else {
            s_xp3[j - 2 * UU]  = xp;
            s_rec3[j - 2 * UU] = rec;
        }
        __syncthreads();

        if (j < UU) {
            float z  = 1.f / (1.f + __expf(-s_zsum[j]));
            float r  = 1.f / (1.f + __expf(-s_rsum[j]));
            float hh = s_xp3[j] + r * s_rec3[j];
            hh = hh > 0.f ? hh : 0.f;
            float hn = z * h_s[j] + (1.f - z) * hh;
            h_s[j] = hn;
            seqb[t * UU + j] = hn;
        }
        __syncthreads();
    }

    if (j < UU) out_state1[b * UU + j] = h_s[j];
}

__global__ __launch_bounds__(768) void gru_l2(
    const float* __restrict__ W2, const float* __restrict__ U2,
    const float* __restrict__ b2, float* __restrict__ d_out)
{
    const int b = blockIdx.x;
    const int j = threadIdx.x;

    __shared__ float sbin[N3], sbrec[N3];
    __shared__ float h_s[UU];
    __shared__ float xrow[UU];
    __shared__ float s_zsum[UU], s_rsum[UU], s_xp3[UU], s_rec3[UU];

    sbin[j]  = b2[j];
    sbrec[j] = b2[N3 + j];
    if (j < UU) h_s[j] = 0.f;
    __syncthreads();

    float ureg[NREG];
#pragma unroll
    for (int k = 0; k < NREG; k++) ureg[k] = U2[k * N3 + j];

    const float* seqb = g_seq1 + (size_t)b * TT * UU;

    for (int t = 0; t < TT; t++) {
        if (j < UU) xrow[j] = seqb[t * UU + j];
        __syncthreads();

        // input projection (W2 streamed from L2)
        float xp = sbin[j];
        const float4* x4 = (const float4*)xrow;
#pragma unroll 4
        for (int k4 = 0; k4 < UU / 4; k4++) {
            float4 xv = x4[k4];
            int k = 4 * k4;
            xp += xv.x * W2[(k + 0) * N3 + j] + xv.y * W2[(k + 1) * N3 + j]
                + xv.z * W2[(k + 2) * N3 + j] + xv.w * W2[(k + 3) * N3 + j];
        }

        // recurrent projection
        float rec = sbrec[j];
        const float4* h4 = (const float4*)h_s;
#pragma unroll
        for (int k4 = 0; k4 < NREG / 4; k4++) {
            float4 hv = h4[k4];
            rec += hv.x * ureg[4 * k4 + 0] + hv.y * ureg[4 * k4 + 1]
                 + hv.z * ureg[4 * k4 + 2] + hv.w * ureg[4 * k4 + 3];
        }
#pragma unroll 4
        for (int k4 = NREG / 4; k4 < UU / 4; k4++) {
            float4 hv = h4[k4];
            int k = 4 * k4;
            rec += hv.x * U2[(k + 0) * N3 + j] + hv.y * U2[(k + 1) * N3 + j]
                 + hv.z * U2[(k + 2) * N3 + j] + hv.w * U2[(k + 3) * N3 + j];
        }

        if (j < 2 * UU) {
            float a = xp + rec;
            if (j < UU) s_zsum[j] = a; else s_rsum[j - UU] = a;
        } else {
            s_xp3[j - 2 * UU]  = xp;
            s_rec3[j - 2 * UU] = rec;
        }
        __syncthreads();

        if (j < UU) {
            float z  = 1.f / (1.f + __expf(-s_zsum[j]));
            float r  = 1.f / (1.f + __expf(-s_rsum[j]));
            float hh = s_xp3[j] + r * s_rec3[j];
            hh = hh > 0.f ? hh : 0.f;
            float hn = z * h_s[j] + (1.f - z) * hh;
            h_s[j] = hn;
        }
        __syncthreads();
    }

    if (j < UU) {
        float hn = h_s[j];
        d_out[b * UU + j] = hn;                     // x  (= seq2[:, -1, :])
        d_out[2 * BB * UU + b * UU + j] = hn;       // state2 (same values)
    }
}

extern "C" void kernel_launch(void* const* d_in, const int* in_sizes, int n_in,
                              void* d_out, int out_size, void* d_ws, size_t ws_size,
                              hipStream_t stream) {
    const float* x  = (const float*)d_in[0];
    const float* W1 = (const float*)d_in[1];
    const float* U1 = (const float*)d_in[2];
    const float* b1 = (const float*)d_in[3];
    const float* W2 = (const float*)d_in[4];
    const float* U2 = (const float*)d_in[5];
    const float* b2 = (const float*)d_in[6];
    float* out = (float*)d_out;

    // out layout: [x (64*256) | state1 (64*256) | state2 (64*256)]
    gru_l1<<<BB, 768, 0, stream>>>(x, W1, U1, b1, out + BB * UU);
    gru_l2<<<BB, 768, 0, stream>>>(W2, U2, b2, out);
}

// Round 2
// 41009.622 us; speedup vs baseline: 1.6609x; 1.6609x over previous
//
#include <hip/hip_runtime.h>

#define BB 64
#define TT 2048
#define FF 15
#define UU 256
#define N3 768
#define K4 64                   // 256/4 k-chunks
#define NC4 26                  // chunks cached in VGPRs (104 rows)
#define NL4 4                   // chunks cached in LDS (16 rows, 48 KB)
#define NS4 (K4 - NC4 - NL4)    // 34 chunks streamed from L2 per step

__device__ float  g_seq1[BB * TT * UU];          // 134 MB
__device__ float  g_xp[(size_t)BB * TT * N3];    // 402 MB (reused for xp1 and xp2)
__device__ float4 g_U1t[K4 * N3];
__device__ float4 g_U2t[K4 * N3];

// Transpose U (256x768 row-major) into k4-chunked float4 layout:
// Ut[k4*768 + j] = { U[4k4+0][j], U[4k4+1][j], U[4k4+2][j], U[4k4+3][j] }
__global__ __launch_bounds__(256) void prep_ut(const float* __restrict__ U,
                                               float4* __restrict__ Ut) {
    int idx = blockIdx.x * 256 + threadIdx.x;    // 0 .. 64*768-1
    int k4 = idx / N3, j = idx - k4 * N3;
    Ut[idx] = make_float4(U[(4 * k4 + 0) * N3 + j], U[(4 * k4 + 1) * N3 + j],
                          U[(4 * k4 + 2) * N3 + j], U[(4 * k4 + 3) * N3 + j]);
}

// xp1 = x @ W1 + b_in   (K=15, memory-bound)
__global__ __launch_bounds__(256) void gemm_k15(
    const float* __restrict__ x, const float* __restrict__ W1,
    const float* __restrict__ bin, float* __restrict__ C) {
    __shared__ float xr[8][FF];
    const int m0 = blockIdx.x * 8;
    const int j  = blockIdx.y * 256 + threadIdx.x;
    if (threadIdx.x < 8 * FF) {
        int r = threadIdx.x / FF, k = threadIdx.x - r * FF;
        xr[r][k] = x[(size_t)(m0 + r) * FF + k];
    }
    __syncthreads();
    float wv[FF];
#pragma unroll
    for (int k = 0; k < FF; k++) wv[k] = W1[k * N3 + j];
    const float bj = bin[j];
#pragma unroll
    for (int r = 0; r < 8; r++) {
        float a = bj;
#pragma unroll
        for (int k = 0; k < FF; k++) a += xr[r][k] * wv[k];
        C[(size_t)(m0 + r) * N3 + j] = a;
    }
}

// xp2 = seq1 @ W2 + b_in   (M=131072, N=768, K=256) tiled fp32 GEMM
__global__ __launch_bounds__(256) void gemm_xp(
    const float* __restrict__ A,   // [M,256]
    const float* __restrict__ Bw,  // [256,768]
    const float* __restrict__ bin, // [768]
    float* __restrict__ C) {       // [M,768]
    __shared__ float As[16][64];   // As[k][m]
    __shared__ float Bs[16][64];   // Bs[k][n]
    const int tid = threadIdx.x;
    const int m0 = blockIdx.x * 64, n0 = blockIdx.y * 64;
    const int tm = (tid & 15) * 4;
    const int tn = (tid >> 4) * 4;
    float acc[4][4] = {};
    const int lm = tid >> 2, lk = (tid & 3) * 4;    // A load: 64 x 16
    const int lkb = tid >> 4, ln = (tid & 15) * 4;  // B load: 16 x 64
    for (int k0 = 0; k0 < 256; k0 += 16) {
        float4 av = *(const float4*)&A[(size_t)(m0 + lm) * 256 + k0 + lk];
        float4 bv = *(const float4*)&Bw[(size_t)(k0 + lkb) * N3 + n0 + ln];
        As[lk + 0][lm] = av.x; As[lk + 1][lm] = av.y;
        As[lk + 2][lm] = av.z; As[lk + 3][lm] = av.w;
        *(float4*)&Bs[lkb][ln] = bv;
        __syncthreads();
#pragma unroll
        for (int kk = 0; kk < 16; kk++) {
            float4 a = *(const float4*)&As[kk][tm];
            float4 b = *(const float4*)&Bs[kk][tn];
            acc[0][0] += a.x * b.x; acc[0][1] += a.x * b.y; acc[0][2] += a.x * b.z; acc[0][3] += a.x * b.w;
            acc[1][0] += a.y * b.x; acc[1][1] += a.y * b.y; acc[1][2] += a.y * b.z; acc[1][3] += a.y * b.w;
            acc[2][0] += a.z * b.x; acc[2][1] += a.z * b.y; acc[2][2] += a.z * b.z; acc[2][3] += a.z * b.w;
            acc[3][0] += a.w * b.x; acc[3][1] += a.w * b.y; acc[3][2] += a.w * b.z; acc[3][3] += a.w * b.w;
        }
        __syncthreads();
    }
#pragma unroll
    for (int i = 0; i < 4; i++) {
        float4 o = make_float4(acc[i][0] + bin[n0 + tn + 0], acc[i][1] + bin[n0 + tn + 1],
                               acc[i][2] + bin[n0 + tn + 2], acc[i][3] + bin[n0 + tn + 3]);
        *(float4*)&C[(size_t)(m0 + tm + i) * N3 + n0 + tn] = o;
    }
}

// Sequential GRU recurrence. One WG (768 threads) per batch element.
// Thread j owns column j of U. U rows 0..103 in VGPRs, 104..119 in LDS,
// 120..255 streamed from L2 with a 4-deep rolling prefetch.
__global__ __launch_bounds__(768, 3) void gru_recur(
    const float4* __restrict__ Ut, const float* __restrict__ brec,
    const float* __restrict__ xp, float* __restrict__ seq_out,
    float* __restrict__ state_out, float* __restrict__ extra_out) {
    const int b = blockIdx.x, j = threadIdx.x;
    __shared__ __align__(16) float h_s[UU];
    __shared__ float pre[N3];
    __shared__ float xq[UU];
    __shared__ float4 sUc[NL4 * N3];   // 48 KB

#pragma unroll
    for (int c = 0; c < NL4; c++) sUc[c * N3 + j] = Ut[(NC4 + c) * N3 + j];
    float4 ureg[NC4];
#pragma unroll
    for (int c = 0; c < NC4; c++) ureg[c] = Ut[c * N3 + j];
    const float brj = brec[j];
    if (j < UU) h_s[j] = 0.f;
    __syncthreads();

    const float4* __restrict__ Us = Ut + (NC4 + NL4) * N3 + j;
    const float* __restrict__ xpb = xp + (size_t)b * TT * N3;
    const float4* h4 = (const float4*)h_s;

    for (int t = 0; t < TT; t++) {
        float xv = xpb[(size_t)t * N3 + j];          // independent, hides under rec
        float4 acc = make_float4(0.f, 0.f, 0.f, 0.f);
#pragma unroll
        for (int c = 0; c < NC4; c++) {
            float4 hv = h4[c], u = ureg[c];
            acc.x += hv.x * u.x; acc.y += hv.y * u.y;
            acc.z += hv.z * u.z; acc.w += hv.w * u.w;
        }
#pragma unroll
        for (int c = 0; c < NL4; c++) {
            float4 hv = h4[NC4 + c], u = sUc[c * N3 + j];
            acc.x += hv.x * u.x; acc.y += hv.y * u.y;
            acc.z += hv.z * u.z; acc.w += hv.w * u.w;
        }
        float4 buf[4];
#pragma unroll
        for (int i = 0; i < 4; i++) buf[i] = Us[i * N3];
#pragma unroll
        for (int c = 0; c < NS4; c++) {
            float4 u = buf[c & 3];
            if (c + 4 < NS4) buf[c & 3] = Us[(c + 4) * N3];
            float4 hv = h4[NC4 + NL4 + c];
            acc.x += hv.x * u.x; acc.y += hv.y * u.y;
            acc.z += hv.z * u.z; acc.w += hv.w * u.w;
        }
        float r1 = acc.x + acc.y + acc.z + acc.w + brj;
        if (j < 2 * UU) pre[j] = r1 + xv;
        else { pre[j] = r1; xq[j - 2 * UU] = xv; }
        __syncthreads();
        if (j < UU) {
            float z = 1.f / (1.f + __expf(-pre[j]));
            float r = 1.f / (1.f + __expf(-pre[UU + j]));
            float hh = xq[j] + r * pre[2 * UU + j];
            hh = hh > 0.f ? hh : 0.f;
            float hn = z * h_s[j] + (1.f - z) * hh;
            h_s[j] = hn;
            if (seq_out) seq_out[(size_t)b * TT * UU + (size_t)t * UU + j] = hn;
        }
        __syncthreads();
    }
    if (j < UU) {
        float hn = h_s[j];
        state_out[b * UU + j] = hn;
        if (extra_out) extra_out[b * UU + j] = hn;
    }
}

extern "C" void kernel_launch(void* const* d_in, const int* in_sizes, int n_in,
                              void* d_out, int out_size, void* d_ws, size_t ws_size,
                              hipStream_t stream) {
    const float* x  = (const float*)d_in[0];
    const float* W1 = (const float*)d_in[1];
    const float* U1 = (const float*)d_in[2];
    const float* b1 = (const float*)d_in[3];
    const float* W2 = (const float*)d_in[4];
    const float* U2 = (const float*)d_in[5];
    const float* b2 = (const float*)d_in[6];
    float* out = (float*)d_out;

    float4* U1t; hipGetSymbolAddress((void**)&U1t, HIP_SYMBOL(g_U1t));
    float4* U2t; hipGetSymbolAddress((void**)&U2t, HIP_SYMBOL(g_U2t));
    float*  seq1; hipGetSymbolAddress((void**)&seq1, HIP_SYMBOL(g_seq1));
    float*  xp;   hipGetSymbolAddress((void**)&xp,   HIP_SYMBOL(g_xp));

    prep_ut<<<K4 * N3 / 256, 256, 0, stream>>>(U1, U1t);
    prep_ut<<<K4 * N3 / 256, 256, 0, stream>>>(U2, U2t);

    // layer 1: xp1 = x@W1 + b1_in, then recurrence (writes seq1, state1)
    gemm_k15<<<dim3(BB * TT / 8, 3), 256, 0, stream>>>(x, W1, b1, xp);
    gru_recur<<<BB, 768, 0, stream>>>(U1t, b1 + N3, xp, seq1, out + BB * UU, nullptr);

    // layer 2: xp2 = seq1@W2 + b2_in, then recurrence (writes x-out and state2)
    gemm_xp<<<dim3(BB * TT / 64, N3 / 64), 256, 0, stream>>>(seq1, W2, b2, xp);
    gru_recur<<<BB, 768, 0, stream>>>(U2t, b2 + N3, xp, nullptr, out + 2 * BB * UU, out);
}

// Round 3
// 5996.735 us; speedup vs baseline: 11.3583x; 6.8387x over previous
//
#include <hip/hip_runtime.h>

#define BB 64
#define TT 2048
#define FF 15
#define UU 256
#define N3 768
#define NP 128          // 128 k-pairs (256 rows) of U per column, in VGPRs as v2f16

typedef _Float16 half2v __attribute__((ext_vector_type(2)));

__device__ float  g_seq1[BB * TT * UU];          // 134 MB
__device__ float  g_xp[(size_t)BB * TT * N3];    // 402 MB (xp1 then xp2)
__device__ half2v g_U1h[NP * N3];
__device__ half2v g_U2h[NP * N3];

__device__ __forceinline__ float dot2f(half2v a, half2v b, float c) {
#if __has_builtin(__builtin_amdgcn_fdot2)
    return __builtin_amdgcn_fdot2(a, b, c, false);
#else
    return c + (float)a.x * (float)b.x + (float)a.y * (float)b.y;
#endif
}

// Pack U (fp32 [256][768]) into k-pair f16 layout: Uh[p*768+j] = {U[2p][j], U[2p+1][j]}
__global__ __launch_bounds__(256) void prep_uh(const float* __restrict__ U,
                                               half2v* __restrict__ Uh) {
    int idx = blockIdx.x * 256 + threadIdx.x;    // 0 .. 128*768-1
    int p = idx / N3, j = idx - p * N3;
    half2v v;
    v.x = (_Float16)U[(2 * p + 0) * N3 + j];
    v.y = (_Float16)U[(2 * p + 1) * N3 + j];
    Uh[idx] = v;
}

// xp1 = x @ W1 + b_in   (K=15, memory-bound)
__global__ __launch_bounds__(256) void gemm_k15(
    const float* __restrict__ x, const float* __restrict__ W1,
    const float* __restrict__ bin, float* __restrict__ C) {
    __shared__ float xr[8][FF];
    const int m0 = blockIdx.x * 8;
    const int j  = blockIdx.y * 256 + threadIdx.x;
    if (threadIdx.x < 8 * FF) {
        int r = threadIdx.x / FF, k = threadIdx.x - r * FF;
        xr[r][k] = x[(size_t)(m0 + r) * FF + k];
    }
    __syncthreads();
    float wv[FF];
#pragma unroll
    for (int k = 0; k < FF; k++) wv[k] = W1[k * N3 + j];
    const float bj = bin[j];
#pragma unroll
    for (int r = 0; r < 8; r++) {
        float a = bj;
#pragma unroll
        for (int k = 0; k < FF; k++) a += xr[r][k] * wv[k];
        C[(size_t)(m0 + r) * N3 + j] = a;
    }
}

// xp2 = seq1 @ W2 + b_in   (M=131072, N=768, K=256) tiled fp32 GEMM
__global__ __launch_bounds__(256) void gemm_xp(
    const float* __restrict__ A, const float* __restrict__ Bw,
    const float* __restrict__ bin, float* __restrict__ C) {
    __shared__ float As[16][64];
    __shared__ float Bs[16][64];
    const int tid = threadIdx.x;
    const int m0 = blockIdx.x * 64, n0 = blockIdx.y * 64;
    const int tm = (tid & 15) * 4;
    const int tn = (tid >> 4) * 4;
    float acc[4][4] = {};
    const int lm = tid >> 2, lk = (tid & 3) * 4;
    const int lkb = tid >> 4, ln = (tid & 15) * 4;
    for (int k0 = 0; k0 < 256; k0 += 16) {
        float4 av = *(const float4*)&A[(size_t)(m0 + lm) * 256 + k0 + lk];
        float4 bv = *(const float4*)&Bw[(size_t)(k0 + lkb) * N3 + n0 + ln];
        As[lk + 0][lm] = av.x; As[lk + 1][lm] = av.y;
        As[lk + 2][lm] = av.z; As[lk + 3][lm] = av.w;
        *(float4*)&Bs[lkb][ln] = bv;
        __syncthreads();
#pragma unroll
        for (int kk = 0; kk < 16; kk++) {
            float4 a = *(const float4*)&As[kk][tm];
            float4 b = *(const float4*)&Bs[kk][tn];
            acc[0][0] += a.x * b.x; acc[0][1] += a.x * b.y; acc[0][2] += a.x * b.z; acc[0][3] += a.x * b.w;
            acc[1][0] += a.y * b.x; acc[1][1] += a.y * b.y; acc[1][2] += a.y * b.z; acc[1][3] += a.y * b.w;
            acc[2][0] += a.z * b.x; acc[2][1] += a.z * b.y; acc[2][2] += a.z * b.z; acc[2][3] += a.z * b.w;
            acc[3][0] += a.w * b.x; acc[3][1] += a.w * b.y; acc[3][2] += a.w * b.z; acc[3][3] += a.w * b.w;
        }
        __syncthreads();
    }
#pragma unroll
    for (int i = 0; i < 4; i++) {
        float4 o = make_float4(acc[i][0] + bin[n0 + tn + 0], acc[i][1] + bin[n0 + tn + 1],
                               acc[i][2] + bin[n0 + tn + 2], acc[i][3] + bin[n0 + tn + 3]);
        *(float4*)&C[(size_t)(m0 + tm + i) * N3 + n0 + tn] = o;
    }
}

// GRU recurrence, one WG per batch element. Thread j owns column j of U,
// whose 256 weights live in 128 v2f16 VGPRs. h is broadcast from LDS as
// packed f16 pairs; gate math and h state stay fp32.
__global__ __launch_bounds__(768, 3) void gru_recur(
    const half2v* __restrict__ Uh, const float* __restrict__ brec,
    const float* __restrict__ xp, float* __restrict__ seq_out,
    float* __restrict__ state_out, float* __restrict__ extra_out) {
    const int b = blockIdx.x, j = threadIdx.x;

    __shared__ __align__(16) half2v h2s[NP];   // packed h (f16 pairs)
    __shared__ float h32[UU];                  // fp32 h state
    __shared__ float xq[N3];
    __shared__ float pre[N3];

    // load U column j into VGPRs
    half2v ureg[NP];
#pragma unroll
    for (int p = 0; p < NP; p++) ureg[p] = Uh[p * N3 + j];
    const float brj = brec[j];

    if (j < NP) { half2v z0; z0.x = (_Float16)0.f; z0.y = (_Float16)0.f; h2s[j] = z0; }
    if (j < UU) h32[j] = 0.f;
    __syncthreads();

    const float* __restrict__ xpb = xp + (size_t)b * TT * N3;
    float xv_cur = xpb[j];

    for (int t = 0; t < TT; t++) {
        float xv_next = (t + 1 < TT) ? xpb[(size_t)(t + 1) * N3 + j] : 0.f;

        // rec = brec[j] + sum_k h[k] * U[k][j]   (registers x LDS-broadcast)
        float acc = brj;
        const float4* h2f4 = (const float4*)h2s;
#pragma unroll
        for (int p4 = 0; p4 < NP / 4; p4++) {
            float4 hv = h2f4[p4];
            half2v* hp = (half2v*)&hv;
            acc = dot2f(hp[0], ureg[4 * p4 + 0], acc);
            acc = dot2f(hp[1], ureg[4 * p4 + 1], acc);
            acc = dot2f(hp[2], ureg[4 * p4 + 2], acc);
            acc = dot2f(hp[3], ureg[4 * p4 + 3], acc);
        }
        xq[j]  = xv_cur;
        pre[j] = acc;
        __syncthreads();                        // S1

        if (j < UU) {
            float z  = 1.f / (1.f + __expf(-(xq[j] + pre[j])));
            float r  = 1.f / (1.f + __expf(-(xq[UU + j] + pre[UU + j])));
            float hh = xq[2 * UU + j] + r * pre[2 * UU + j];
            hh = hh > 0.f ? hh : 0.f;
            float hn = z * h32[j] + (1.f - z) * hh;
            h32[j] = hn;
            float hp = __shfl_xor(hn, 1);       // partner unit in adjacent lane
            if ((j & 1) == 0) {
                half2v pk; pk.x = (_Float16)hn; pk.y = (_Float16)hp;
                h2s[j >> 1] = pk;
            }
            if (seq_out) seq_out[(size_t)b * TT * UU + (size_t)t * UU + j] = hn;
        }
        __syncthreads();                        // S2
        xv_cur = xv_next;
    }

    if (j < UU) {
        float hn = h32[j];
        state_out[b * UU + j] = hn;
        if (extra_out) extra_out[b * UU + j] = hn;
    }
}

extern "C" void kernel_launch(void* const* d_in, const int* in_sizes, int n_in,
                              void* d_out, int out_size, void* d_ws, size_t ws_size,
                              hipStream_t stream) {
    const float* x  = (const float*)d_in[0];
    const float* W1 = (const float*)d_in[1];
    const float* U1 = (const float*)d_in[2];
    const float* b1 = (const float*)d_in[3];
    const float* W2 = (const float*)d_in[4];
    const float* U2 = (const float*)d_in[5];
    const float* b2 = (const float*)d_in[6];
    float* out = (float*)d_out;

    half2v* U1h; hipGetSymbolAddress((void**)&U1h, HIP_SYMBOL(g_U1h));
    half2v* U2h; hipGetSymbolAddress((void**)&U2h, HIP_SYMBOL(g_U2h));
    float*  seq1; hipGetSymbolAddress((void**)&seq1, HIP_SYMBOL(g_seq1));
    float*  xp;   hipGetSymbolAddress((void**)&xp,   HIP_SYMBOL(g_xp));

    prep_uh<<<NP * N3 / 256, 256, 0, stream>>>(U1, U1h);
    prep_uh<<<NP * N3 / 256, 256, 0, stream>>>(U2, U2h);

    // layer 1
    gemm_k15<<<dim3(BB * TT / 8, 3), 256, 0, stream>>>(x, W1, b1, xp);
    gru_recur<<<BB, 768, 0, stream>>>(U1h, b1 + N3, xp, seq1, out + BB * UU, nullptr);

    // layer 2
    gemm_xp<<<dim3(BB * TT / 64, N3 / 64), 256, 0, stream>>>(seq1, W2, b2, xp);
    gru_recur<<<BB, 768, 0, stream>>>(U2h, b2 + N3, xp, nullptr, out + 2 * BB * UU, out);
}